// Round 16
// baseline (326.936 us; speedup 1.0000x reference)
//
#include <hip/hip_runtime.h>

// R16 (resubmit; prior round hit GPU-acquisition timeout, never measured):
// R15 (325.6us, new best; reduce ~96us by subtraction) with phase-2
// of the reduce widened from 2 to 4 concurrent rows per wave -> 16
// independent float4 loads in flight per lane-phase (was 8), 2 phases
// (was 4). Single-variable MLP experiment on the last attackable term:
// the 205MB random-256B gather running at 2.1 TB/s effective.
// If unchanged -> random-gather HW wall -> declare roofline.
// K1-K4 and reduce phase 1 byte-identical to R15.
// Constraints: N <= 65536; within-row order arbitrary (tol 0.0625).

#define SHIFT  6                  // bucket = row >> 6 (64 rows/bucket)
#define WROWS  64
#define SCAP   2048               // sid capacity (max bucket ~1170 for this input)
#define CEDGE  4096               // edges per hist/scatter block (1024 thr x 4)
#define SELEM  16                 // scan elems/thread
#define STILE  4096               // scan tile: 256 threads x 16

// K1: per-chunk bucket histogram -> cnt[bucket * nblk + blk]
__global__ __launch_bounds__(1024) void bucket_hist(
    const int* __restrict__ edge0, int* __restrict__ cnt,
    int E, int nblk, int NB)
{
    __shared__ int lh[1024];
    int t = threadIdx.x, blk = blockIdx.x;
    lh[t] = 0;
    __syncthreads();
    int idx4 = blk * 1024 + t;
    int base = idx4 * 4;
    if (base + 3 < E) {
        int4 r = ((const int4*)edge0)[idx4];
        atomicAdd(&lh[r.x >> SHIFT], 1);
        atomicAdd(&lh[r.y >> SHIFT], 1);
        atomicAdd(&lh[r.z >> SHIFT], 1);
        atomicAdd(&lh[r.w >> SHIFT], 1);
    } else {
        for (int i = base; i < E && i < base + 4; ++i)
            atomicAdd(&lh[edge0[i] >> SHIFT], 1);
    }
    __syncthreads();
    if (t < NB) cnt[t * nblk + blk] = lh[t];
}

// K2/K3: 2-dispatch exclusive scan of M ints (M=153272 -> 38 tiles <= 64).
__global__ __launch_bounds__(256) void scan_partial(
    const int* __restrict__ a, int* __restrict__ tileSum, int M)
{
    __shared__ int wsum[4];
    int t = threadIdx.x;
    int base = blockIdx.x * STILE + t * SELEM;
    int s = 0;
    #pragma unroll
    for (int k = 0; k < SELEM; ++k) {
        int i = base + k;
        if (i < M) s += a[i];
    }
    for (int off = 1; off < 64; off <<= 1) s += __shfl_xor(s, off);
    if ((t & 63) == 0) wsum[t >> 6] = s;
    __syncthreads();
    if (t == 0) tileSum[blockIdx.x] = wsum[0] + wsum[1] + wsum[2] + wsum[3];
}

__global__ __launch_bounds__(256) void scan_final(
    const int* __restrict__ a, const int* __restrict__ tileSum,
    int* __restrict__ ax, int M, int numTiles)
{
    __shared__ int wtot[4];
    __shared__ int tilePre;
    int t = threadIdx.x;
    int lane = t & 63, wv = t >> 6;

    if (t < 64) {                            // wave 0: scan tile sums
        int v0 = (t < numTiles) ? tileSum[t] : 0;
        int v = v0;
        #pragma unroll
        for (int off = 1; off < 64; off <<= 1) {
            int u = __shfl_up(v, off);
            if (t >= off) v += u;
        }
        if (t == blockIdx.x) tilePre = v - v0;   // exclusive prefix of this tile
    }

    int base = blockIdx.x * STILE + t * SELEM;
    int c[SELEM]; int s = 0;
    #pragma unroll
    for (int k = 0; k < SELEM; ++k) {
        int i = base + k;
        c[k] = (i < M) ? a[i] : 0;
        s += c[k];
    }
    int inc = s;
    #pragma unroll
    for (int off = 1; off < 64; off <<= 1) {
        int u = __shfl_up(inc, off);
        if (lane >= off) inc += u;
    }
    if (lane == 63) wtot[wv] = inc;
    __syncthreads();
    int wpre = 0;
    for (int w = 0; w < wv; ++w) wpre += wtot[w];
    int pre = tilePre + wpre + (inc - s);
    #pragma unroll
    for (int k = 0; k < SELEM; ++k) {
        int i = base + k;
        if (i < M) ax[i] = pre;
        pre += c[k];
    }
}

// K4: direct scatter — LDS rank + fire-and-forget int2 store at gb[bucket]+rank.
__global__ __launch_bounds__(1024) void scatter_direct(
    const int* __restrict__ edge0, const int* __restrict__ cntX,
    int2* __restrict__ recs, int E, int nblk, int NB)
{
    __shared__ int lh[1024];
    __shared__ int gb[1024];
    int t = threadIdx.x, blk = blockIdx.x;
    lh[t] = 0;
    if (t < NB) gb[t] = cntX[t * nblk + blk];
    __syncthreads();
    int idx4 = blk * 1024 + t;
    int base = idx4 * 4;
    if (base + 3 < E) {
        int4 r = ((const int4*)edge0)[idx4];
        int b0 = r.x >> SHIFT, b1 = r.y >> SHIFT;
        int b2 = r.z >> SHIFT, b3 = r.w >> SHIFT;
        int k0 = atomicAdd(&lh[b0], 1);
        int k1 = atomicAdd(&lh[b1], 1);
        int k2 = atomicAdd(&lh[b2], 1);
        int k3 = atomicAdd(&lh[b3], 1);
        recs[gb[b0] + k0] = make_int2(r.x, base + 0);
        recs[gb[b1] + k1] = make_int2(r.y, base + 1);
        recs[gb[b2] + k2] = make_int2(r.z, base + 2);
        recs[gb[b3] + k3] = make_int2(r.w, base + 3);
    } else {
        for (int i = base; i < E && i < base + 4; ++i) {
            int rr = edge0[i];
            int b = rr >> SHIFT;
            int k = atomicAdd(&lh[b], 1);
            recs[gb[b] + k] = make_int2(rr, i);
        }
    }
}

// K5: one block (512 thr = 8 waves) per bucket. Phase 1: LDS row-sort
// (hist + wave-0 scan + rank-scatter ids into sid) — unchanged from R15.
// Phase 2 (R16): wave wv gathers FOUR rows {wv, wv+8, wv+16, wv+24}+32k
// concurrently: 8 slots x 8 feature-lanes, 2 batches x 4 rows -> 16
// independent float4 loads in flight; register accum; xor-shuffle; write.
__global__ __launch_bounds__(512) void bucket_csr_reduce(
    const int* __restrict__ cntX, const int2* __restrict__ recs,
    const float4* __restrict__ w4, float4* __restrict__ out4,
    int E, int nblk, int NB, int N)
{
    __shared__ int rcnt[WROWS];
    __shared__ int rfill[WROWS];
    __shared__ int rpre[WROWS];
    __shared__ int sid[SCAP];
    int t = threadIdx.x, b = blockIdx.x;
    int lane = t & 63, wv = t >> 6;          // 8 waves
    int sub = lane >> 3, g = lane & 7;       // slot, feature-octet
    int S0 = cntX[b * nblk];
    int S1 = (b + 1 < NB) ? cntX[(b + 1) * nblk] : E;
    int cnt = S1 - S0;

    if (t < WROWS) { rcnt[t] = 0; rfill[t] = 0; }
    __syncthreads();

    for (int k = t; k < cnt; k += 512)
        atomicAdd(&rcnt[recs[S0 + k].x & (WROWS - 1)], 1);
    __syncthreads();

    if (t < 64) {                             // wave-0 exclusive scan of rcnt
        int v = rcnt[t], inc = v;
        #pragma unroll
        for (int off = 1; off < 64; off <<= 1) {
            int u = __shfl_up(inc, off);
            if (t >= off) inc += u;
        }
        rpre[t] = inc - v;
    }
    __syncthreads();

    for (int k = t; k < cnt; k += 512) {
        int2 r = recs[S0 + k];
        int lr = r.x & (WROWS - 1);
        int pos = rpre[lr] + atomicAdd(&rfill[lr], 1);
        if (pos < SCAP) sid[pos] = r.y;
        else {  // unreachable for this input (max bucket ~1170 < 2048)
            const float* wp = (const float*)(w4 + (size_t)r.y * 16);
            float* op = (float*)out4 + (size_t)r.x * 64;
            for (int c = 0; c < 64; ++c) atomicAdd(op + c, wp[c]);
        }
    }
    __syncthreads();

    int r0 = b << SHIFT;
    #pragma unroll
    for (int k = 0; k < 2; ++k) {            // 2 quads per wave
        int rA = wv      + k * 32, rB = wv + 8  + k * 32;
        int rC = wv + 16 + k * 32, rD = wv + 24 + k * 32;
        int begA = rpre[rA], cA = rcnt[rA];
        int begB = rpre[rB], cB = rcnt[rB];
        int begC = rpre[rC], cC = rcnt[rC];
        int begD = rpre[rD], cD = rcnt[rD];
        { int cap = SCAP - begA; if (cap < 0) cap = 0; if (cA > cap) cA = cap; }
        { int cap = SCAP - begB; if (cap < 0) cap = 0; if (cB > cap) cB = cap; }
        { int cap = SCAP - begC; if (cap < 0) cap = 0; if (cC > cap) cC = cap; }
        { int cap = SCAP - begD; if (cap < 0) cap = 0; if (cD > cap) cD = cap; }

        int j0 = sub, j1 = 8 + sub;
        int eA0 = (cA > 0) ? sid[begA + (j0 < cA ? j0 : cA - 1)] : 0;
        int eA1 = (cA > 0) ? sid[begA + (j1 < cA ? j1 : cA - 1)] : 0;
        int eB0 = (cB > 0) ? sid[begB + (j0 < cB ? j0 : cB - 1)] : 0;
        int eB1 = (cB > 0) ? sid[begB + (j1 < cB ? j1 : cB - 1)] : 0;
        int eC0 = (cC > 0) ? sid[begC + (j0 < cC ? j0 : cC - 1)] : 0;
        int eC1 = (cC > 0) ? sid[begC + (j1 < cC ? j1 : cC - 1)] : 0;
        int eD0 = (cD > 0) ? sid[begD + (j0 < cD ? j0 : cD - 1)] : 0;
        int eD1 = (cD > 0) ? sid[begD + (j1 < cD ? j1 : cD - 1)] : 0;
        // 16 independent float4 loads in flight
        const float4* pA0 = w4 + (size_t)eA0 * 16;
        const float4* pA1 = w4 + (size_t)eA1 * 16;
        const float4* pB0 = w4 + (size_t)eB0 * 16;
        const float4* pB1 = w4 + (size_t)eB1 * 16;
        const float4* pC0 = w4 + (size_t)eC0 * 16;
        const float4* pC1 = w4 + (size_t)eC1 * 16;
        const float4* pD0 = w4 + (size_t)eD0 * 16;
        const float4* pD1 = w4 + (size_t)eD1 * 16;
        float4 vA00 = pA0[g * 2], vA01 = pA0[g * 2 + 1];
        float4 vA10 = pA1[g * 2], vA11 = pA1[g * 2 + 1];
        float4 vB00 = pB0[g * 2], vB01 = pB0[g * 2 + 1];
        float4 vB10 = pB1[g * 2], vB11 = pB1[g * 2 + 1];
        float4 vC00 = pC0[g * 2], vC01 = pC0[g * 2 + 1];
        float4 vC10 = pC1[g * 2], vC11 = pC1[g * 2 + 1];
        float4 vD00 = pD0[g * 2], vD01 = pD0[g * 2 + 1];
        float4 vD10 = pD1[g * 2], vD11 = pD1[g * 2 + 1];

        float4 aZ = make_float4(0.f, 0.f, 0.f, 0.f);
        float4 a0 = aZ, a1 = aZ, b0 = aZ, b1 = aZ;
        float4 c0 = aZ, c1 = aZ, d0 = aZ, d1 = aZ;
        if (j0 < cA) { a0.x+=vA00.x; a0.y+=vA00.y; a0.z+=vA00.z; a0.w+=vA00.w;
                       a1.x+=vA01.x; a1.y+=vA01.y; a1.z+=vA01.z; a1.w+=vA01.w; }
        if (j1 < cA) { a0.x+=vA10.x; a0.y+=vA10.y; a0.z+=vA10.z; a0.w+=vA10.w;
                       a1.x+=vA11.x; a1.y+=vA11.y; a1.z+=vA11.z; a1.w+=vA11.w; }
        if (j0 < cB) { b0.x+=vB00.x; b0.y+=vB00.y; b0.z+=vB00.z; b0.w+=vB00.w;
                       b1.x+=vB01.x; b1.y+=vB01.y; b1.z+=vB01.z; b1.w+=vB01.w; }
        if (j1 < cB) { b0.x+=vB10.x; b0.y+=vB10.y; b0.z+=vB10.z; b0.w+=vB10.w;
                       b1.x+=vB11.x; b1.y+=vB11.y; b1.z+=vB11.z; b1.w+=vB11.w; }
        if (j0 < cC) { c0.x+=vC00.x; c0.y+=vC00.y; c0.z+=vC00.z; c0.w+=vC00.w;
                       c1.x+=vC01.x; c1.y+=vC01.y; c1.z+=vC01.z; c1.w+=vC01.w; }
        if (j1 < cC) { c0.x+=vC10.x; c0.y+=vC10.y; c0.z+=vC10.z; c0.w+=vC10.w;
                       c1.x+=vC11.x; c1.y+=vC11.y; c1.z+=vC11.z; c1.w+=vC11.w; }
        if (j0 < cD) { d0.x+=vD00.x; d0.y+=vD00.y; d0.z+=vD00.z; d0.w+=vD00.w;
                       d1.x+=vD01.x; d1.y+=vD01.y; d1.z+=vD01.z; d1.w+=vD01.w; }
        if (j1 < cD) { d0.x+=vD10.x; d0.y+=vD10.y; d0.z+=vD10.z; d0.w+=vD10.w;
                       d1.x+=vD11.x; d1.y+=vD11.y; d1.z+=vD11.z; d1.w+=vD11.w; }

        for (int j = 16 + sub; j < cA; j += 8) {     // rare tails (deg > 16)
            const float4* p = w4 + (size_t)sid[begA + j] * 16;
            float4 v0 = p[g * 2], v1 = p[g * 2 + 1];
            a0.x+=v0.x; a0.y+=v0.y; a0.z+=v0.z; a0.w+=v0.w;
            a1.x+=v1.x; a1.y+=v1.y; a1.z+=v1.z; a1.w+=v1.w;
        }
        for (int j = 16 + sub; j < cB; j += 8) {
            const float4* p = w4 + (size_t)sid[begB + j] * 16;
            float4 v0 = p[g * 2], v1 = p[g * 2 + 1];
            b0.x+=v0.x; b0.y+=v0.y; b0.z+=v0.z; b0.w+=v0.w;
            b1.x+=v1.x; b1.y+=v1.y; b1.z+=v1.z; b1.w+=v1.w;
        }
        for (int j = 16 + sub; j < cC; j += 8) {
            const float4* p = w4 + (size_t)sid[begC + j] * 16;
            float4 v0 = p[g * 2], v1 = p[g * 2 + 1];
            c0.x+=v0.x; c0.y+=v0.y; c0.z+=v0.z; c0.w+=v0.w;
            c1.x+=v1.x; c1.y+=v1.y; c1.z+=v1.z; c1.w+=v1.w;
        }
        for (int j = 16 + sub; j < cD; j += 8) {
            const float4* p = w4 + (size_t)sid[begD + j] * 16;
            float4 v0 = p[g * 2], v1 = p[g * 2 + 1];
            d0.x+=v0.x; d0.y+=v0.y; d0.z+=v0.z; d0.w+=v0.w;
            d1.x+=v1.x; d1.y+=v1.y; d1.z+=v1.z; d1.w+=v1.w;
        }

        #pragma unroll
        for (int m = 8; m < 64; m <<= 1) {
            a0.x += __shfl_xor(a0.x, m); a0.y += __shfl_xor(a0.y, m);
            a0.z += __shfl_xor(a0.z, m); a0.w += __shfl_xor(a0.w, m);
            a1.x += __shfl_xor(a1.x, m); a1.y += __shfl_xor(a1.y, m);
            a1.z += __shfl_xor(a1.z, m); a1.w += __shfl_xor(a1.w, m);
            b0.x += __shfl_xor(b0.x, m); b0.y += __shfl_xor(b0.y, m);
            b0.z += __shfl_xor(b0.z, m); b0.w += __shfl_xor(b0.w, m);
            b1.x += __shfl_xor(b1.x, m); b1.y += __shfl_xor(b1.y, m);
            b1.z += __shfl_xor(b1.z, m); b1.w += __shfl_xor(b1.w, m);
            c0.x += __shfl_xor(c0.x, m); c0.y += __shfl_xor(c0.y, m);
            c0.z += __shfl_xor(c0.z, m); c0.w += __shfl_xor(c0.w, m);
            c1.x += __shfl_xor(c1.x, m); c1.y += __shfl_xor(c1.y, m);
            c1.z += __shfl_xor(c1.z, m); c1.w += __shfl_xor(c1.w, m);
            d0.x += __shfl_xor(d0.x, m); d0.y += __shfl_xor(d0.y, m);
            d0.z += __shfl_xor(d0.z, m); d0.w += __shfl_xor(d0.w, m);
            d1.x += __shfl_xor(d1.x, m); d1.y += __shfl_xor(d1.y, m);
            d1.z += __shfl_xor(d1.z, m); d1.w += __shfl_xor(d1.w, m);
        }
        if (sub == 0) {
            int grA = r0 + rA, grB = r0 + rB, grC = r0 + rC, grD = r0 + rD;
            if (grA < N) { out4[(size_t)grA * 16 + g * 2] = a0;
                           out4[(size_t)grA * 16 + g * 2 + 1] = a1; }
            if (grB < N) { out4[(size_t)grB * 16 + g * 2] = b0;
                           out4[(size_t)grB * 16 + g * 2 + 1] = b1; }
            if (grC < N) { out4[(size_t)grC * 16 + g * 2] = c0;
                           out4[(size_t)grC * 16 + g * 2 + 1] = c1; }
            if (grD < N) { out4[(size_t)grD * 16 + g * 2] = d0;
                           out4[(size_t)grD * 16 + g * 2 + 1] = d1; }
        }
    }
}

extern "C" void kernel_launch(void* const* d_in, const int* in_sizes, int n_in,
                              void* d_out, int out_size, void* d_ws, size_t ws_size,
                              hipStream_t stream) {
    const int*   edge   = (const int*)d_in[0];     // (2,E) int32; rows = edge[0,:]
    const float* edge_w = (const float*)d_in[1];   // (E, 64) float32
    int E = in_sizes[0] / 2;
    int N = out_size / 64;
    int nblk = (E + CEDGE - 1) / CEDGE;            // 196 for E=800000
    int NB   = (N + WROWS - 1) / WROWS;            // 782 for N=50000 (<=1024)
    int M    = NB * nblk;                          // 153272
    int numTiles = (M + STILE - 1) / STILE;        // 38 (must be <=64)

    // Workspace (ints): recs[2E] | cntS[M] | cntX[M] | tileSum[64]
    int* recs    = (int*)d_ws;                     // int2[E], 8B-aligned at base
    int* cntS    = recs + 2 * (size_t)E;
    int* cntX    = cntS + M;
    int* tileSum = cntX + M;

    bucket_hist     <<<nblk, 1024, 0, stream>>>(edge, cntS, E, nblk, NB);
    scan_partial    <<<numTiles, 256, 0, stream>>>(cntS, tileSum, M);
    scan_final      <<<numTiles, 256, 0, stream>>>(cntS, tileSum, cntX, M, numTiles);
    scatter_direct  <<<nblk, 1024, 0, stream>>>(edge, cntX, (int2*)recs, E, nblk, NB);
    bucket_csr_reduce<<<NB, 512, 0, stream>>>(cntX, (const int2*)recs,
                                              (const float4*)edge_w, (float4*)d_out,
                                              E, nblk, NB, N);
}